// Round 2
// baseline (622.536 us; speedup 1.0000x reference)
//
#include <hip/hip_runtime.h>
#include <hip/hip_cooperative_groups.h>

namespace cg = cooperative_groups;

#define N_NODES 100000
#define N_EDGES 1600000
#define D 64
#define H 128
#define SCAN_BS 512
#define SCAN_NBLK ((N_NODES + SCAN_BS - 1) / SCAN_BS)   // 196

// bucket pipeline: 32-node buckets, exact cover of 100000 nodes
#define BK 32
#define NB2 3125                 // 3125 * 32 == 100000 exactly
#define BCAP2 1536               // LDS edge cap per tile (avg bucket = 512 edges)

#define MFMA_GRID 768
#define SH_STRIDE 132            // fp32 fallback MLP
#define SH16_ST 136              // bf16 sh stride

typedef __attribute__((ext_vector_type(8))) short short8;
typedef __attribute__((ext_vector_type(4))) float floatx4;
typedef __attribute__((ext_vector_type(4))) unsigned short ushort4_t;
typedef __attribute__((ext_vector_type(8))) unsigned short ushort8_t;

__device__ __forceinline__ unsigned short f2bf(float f) {
    unsigned u = __builtin_bit_cast(unsigned, f);
    u += 0x7FFFu + ((u >> 16) & 1u);
    return (unsigned short)(u >> 16);
}
__device__ __forceinline__ float bf2f(unsigned short u) {
    unsigned v = ((unsigned)u) << 16;
    return __builtin_bit_cast(float, v);
}

// ===========================================================================
// Phase bodies, shared between the cooperative mega-kernel and the
// non-cooperative fallback split.
// ===========================================================================

// P1: global-atomic bucket histogram + x fp32->bf16 + W1/W2 -> MFMA layout.
__device__ __forceinline__ void phase_pre(const float* x, unsigned short* x16,
                                          const int* dst,
                                          const float* W1, const float* W2,
                                          unsigned short* gW1b,
                                          unsigned short* gW2b,
                                          int* bhist) {
    int t = threadIdx.x;
    int stride = gridDim.x * 256;
    int start = blockIdx.x * 256 + t;

    for (int i = start; i < N_EDGES; i += stride)
        atomicAdd(&bhist[dst[i] >> 5], 1);       // fire-and-forget

    const float4* x4 = (const float4*)x;
    ushort4_t* y = (ushort4_t*)x16;
    const int n4 = N_NODES * D / 4;
    for (int i = start; i < n4; i += stride) {
        float4 v = x4[i];
        ushort4_t o;
        o[0] = f2bf(v.x); o[1] = f2bf(v.y); o[2] = f2bf(v.z); o[3] = f2bf(v.w);
        y[i] = o;
    }

    if (blockIdx.x == 0) {
        for (int q = t; q < 8192; q += 256) {
            int j = q & 7, l = (q >> 3) & 63, f = q >> 9;
            int nt = f & 7, kt = f >> 3;
            int k = kt * 32 + ((l >> 4) << 3) + j;
            int n = nt * 16 + (l & 15);
            gW1b[q] = f2bf(W1[k * H + n]);
        }
    } else if (blockIdx.x == 1) {
        for (int q = t; q < 8192; q += 256) {
            int j = q & 7, l = (q >> 3) & 63, f = q >> 9;
            int nt = f & 3, kt = f >> 2;
            int k = kt * 32 + ((l >> 4) << 3) + j;
            int n = nt * 16 + (l & 15);
            gW2b[q] = f2bf(W2[k * D + n]);
        }
    }
}

// Per-block local exclusive scan of bhist[NB2] -> sstart[NB2+1] in LDS.
// Redundant per block (~13KB read, L2-hot) -- removes two global scan passes.
__device__ __forceinline__ void phase_scan(const int* bhist, int* sstart,
                                           int* spart) {
    int t = threadIdx.x;
    int base = t * 13;                           // 13*256 = 3328 >= 3125
    int v[13];
    int s = 0;
#pragma unroll
    for (int j = 0; j < 13; j++) {
        int idx = base + j;
        v[j] = (idx < NB2) ? bhist[idx] : 0;
        s += v[j];
    }
    spart[t] = s;
    __syncthreads();
    for (int off = 1; off < 256; off <<= 1) {
        int u = (t >= off) ? spart[t - off] : 0;
        __syncthreads();
        spart[t] += u;
        __syncthreads();
    }
    int run = (t > 0) ? spart[t - 1] : 0;
#pragma unroll
    for (int j = 0; j < 13; j++) {
        int idx = base + j;
        if (idx < NB2) sstart[idx] = run;
        run += v[j];
    }
    if (t == 0) sstart[NB2] = N_EDGES;
    __syncthreads();
}

// P2: partition edges into bucket-ordered ebuf via global atomic cursors
// (ccur pre-zeroed by a memset node). Packed (dlow<<17)|src.
__device__ __forceinline__ void phase_part(const int* src, const int* dst,
                                           const int* sstart, int* ccur,
                                           int* ebuf) {
    int t = threadIdx.x;
    int stride = gridDim.x * 256;
    for (int i = blockIdx.x * 256 + t; i < N_EDGES; i += stride) {
        int d = dst[i], s = src[i];
        int b = d >> 5;
        int p = sstart[b] + atomicAdd(&ccur[b], 1);
        ebuf[p] = s | ((d & 31) << 17);
    }
}

// P3: grid-stride over 32-node buckets. Tiled mini-CSR in LDS (no overflow
// path: register accumulators persist across BCAP2 tiles). One node per
// 8-lane group; 16B bf16 gather loads; epilogue adds fp32 x, writes bf16 o16.
__device__ __forceinline__ void phase_bagg(const float* x,
                                           const unsigned short* x16,
                                           const int* ebuf, const int* sstart,
                                           int* scur, int* snd, int* slist,
                                           unsigned short* o16) {
    int t = threadIdx.x;
    int g = t >> 3;                  // node-in-bucket 0..31
    int l8 = t & 7;                  // feature octet
    for (int b = blockIdx.x; b < NB2; b += gridDim.x) {
        int estart = sstart[b];
        int ne = sstart[b + 1] - estart;
        const int* ep = ebuf + estart;
        float accA[8], accB[8];
#pragma unroll
        for (int j = 0; j < 8; j++) { accA[j] = 0.f; accB[j] = 0.f; }

        int ntile = (ne + BCAP2 - 1) / BCAP2;    // ==1 for Poisson(512)
        for (int T = 0; T < ntile; T++) {
            int toff = T * BCAP2;
            int tn = ne - toff;
            if (tn > BCAP2) tn = BCAP2;
            __syncthreads();                     // protects prev slist use
            if (t < BK) scur[t] = 0;
            __syncthreads();
            for (int i = t; i < tn; i += 256)
                atomicAdd(&scur[ep[toff + i] >> 17], 1);
            __syncthreads();
            if (t < BK) {
                int v = scur[t], s = v;
#pragma unroll
                for (int off = 1; off < BK; off <<= 1) {
                    int u = __shfl_up(s, off, 64);
                    if (t >= off) s += u;
                }
                snd[t] = s;
                scur[t] = s - v;                 // exclusive start -> cursor
            }
            __syncthreads();
            for (int i = t; i < tn; i += 256) {
                int v = ep[toff + i];
                int p = atomicAdd(&scur[v >> 17], 1);
                slist[p] = v & 0x1FFFF;
            }
            __syncthreads();

            int s0 = (g > 0) ? snd[g - 1] : 0;
            int e1 = snd[g];
            int i2 = s0;
            for (; i2 + 4 <= e1; i2 += 4) {
                int sA = slist[i2], sB = slist[i2 + 1];
                int sC = slist[i2 + 2], sD = slist[i2 + 3];
                ushort8_t uA = *(const ushort8_t*)&x16[(size_t)sA * D + l8 * 8];
                ushort8_t uB = *(const ushort8_t*)&x16[(size_t)sB * D + l8 * 8];
                ushort8_t uC = *(const ushort8_t*)&x16[(size_t)sC * D + l8 * 8];
                ushort8_t uD = *(const ushort8_t*)&x16[(size_t)sD * D + l8 * 8];
#pragma unroll
                for (int j = 0; j < 8; j++) accA[j] += bf2f(uA[j]);
#pragma unroll
                for (int j = 0; j < 8; j++) accB[j] += bf2f(uB[j]);
#pragma unroll
                for (int j = 0; j < 8; j++) accA[j] += bf2f(uC[j]);
#pragma unroll
                for (int j = 0; j < 8; j++) accB[j] += bf2f(uD[j]);
            }
            for (; i2 < e1; i2++) {
                ushort8_t uA =
                    *(const ushort8_t*)&x16[(size_t)slist[i2] * D + l8 * 8];
#pragma unroll
                for (int j = 0; j < 8; j++) accA[j] += bf2f(uA[j]);
            }
        }

        int node = b * BK + g;                   // always < N_NODES (exact)
        const float* xp = x + (size_t)node * D + l8 * 8;
        float4 x0 = *(const float4*)xp;
        float4 x1 = *(const float4*)(xp + 4);
        ushort8_t o;
        o[0] = f2bf(accA[0] + accB[0] + x0.x);
        o[1] = f2bf(accA[1] + accB[1] + x0.y);
        o[2] = f2bf(accA[2] + accB[2] + x0.z);
        o[3] = f2bf(accA[3] + accB[3] + x0.w);
        o[4] = f2bf(accA[4] + accB[4] + x1.x);
        o[5] = f2bf(accA[5] + accB[5] + x1.y);
        o[6] = f2bf(accA[6] + accB[6] + x1.z);
        o[7] = f2bf(accA[7] + accB[7] + x1.w);
        *(ushort8_t*)&o16[(size_t)node * D + l8 * 8] = o;
    }
}

// ===========================================================================
// Cooperative mega-kernel: P1 | sync | scan+P2 | sync | P3.
// LDS ~18.9KB, 256 threads; grid clamped to residency at launch.
// ===========================================================================
__global__ __launch_bounds__(256) void k_graph(const float* x,
                                               unsigned short* x16,
                                               const int* src, const int* dst,
                                               const float* W1,
                                               const float* W2,
                                               unsigned short* gW1b,
                                               unsigned short* gW2b,
                                               int* bhist, int* ccur,
                                               int* ebuf,
                                               unsigned short* o16) {
    __shared__ int sstart[NB2 + 1];
    __shared__ int sbuf[2 * BK + BCAP2];     // scur | snd | slist (spart aliases)
    cg::grid_group grid = cg::this_grid();

    phase_pre(x, x16, dst, W1, W2, gW1b, gW2b, bhist);
    grid.sync();
    phase_scan(bhist, sstart, sbuf);
    phase_part(src, dst, sstart, ccur, ebuf);
    grid.sync();
    phase_bagg(x, x16, ebuf, sstart, sbuf, sbuf + BK, sbuf + 2 * BK, o16);
}

// Non-cooperative fallback split (same phases, kernel-boundary sync).
__global__ __launch_bounds__(256) void k_p1(const float* x, unsigned short* x16,
                                            const int* dst, const float* W1,
                                            const float* W2,
                                            unsigned short* gW1b,
                                            unsigned short* gW2b, int* bhist) {
    phase_pre(x, x16, dst, W1, W2, gW1b, gW2b, bhist);
}
__global__ __launch_bounds__(256) void k_p2(const int* src, const int* dst,
                                            const int* bhist, int* ccur,
                                            int* ebuf) {
    __shared__ int sstart[NB2 + 1];
    __shared__ int sbuf[2 * BK + BCAP2];
    phase_scan(bhist, sstart, sbuf);
    phase_part(src, dst, sstart, ccur, ebuf);
}
__global__ __launch_bounds__(256) void k_p3(const float* x,
                                            const unsigned short* x16,
                                            const int* ebuf, const int* bhist,
                                            unsigned short* o16) {
    __shared__ int sstart[NB2 + 1];
    __shared__ int sbuf[2 * BK + BCAP2];
    phase_scan(bhist, sstart, sbuf);
    phase_bagg(x, x16, ebuf, sstart, sbuf, sbuf + BK, sbuf + 2 * BK, o16);
}

// ===========================================================================
// MFMA bf16 fused MLP (R1-proven): bf16 in16, bf16 LDS h-staging, fp32 out.
// ===========================================================================
__global__ __launch_bounds__(256) void k_mlp16(const unsigned short* __restrict__ in16,
                                               float* __restrict__ outp,
                                               const unsigned short* __restrict__ gW1b,
                                               const unsigned short* __restrict__ gW2b,
                                               const float* __restrict__ b1,
                                               const float* __restrict__ b2) {
    __shared__ unsigned short sW1b[8192];
    __shared__ unsigned short sW2b[8192];
    __shared__ unsigned short sh16[4][16 * SH16_ST];
    __shared__ float sb1[H];
    __shared__ float sb2[D];

    int t = threadIdx.x;
    for (int q = t; q < 1024; q += 256) {
        *(short8*)&sW1b[q * 8] = *(const short8*)&gW1b[q * 8];
        *(short8*)&sW2b[q * 8] = *(const short8*)&gW2b[q * 8];
    }
    if (t < H) sb1[t] = b1[t];
    if (t >= H && t < H + D) sb2[t - H] = b2[t - H];
    __syncthreads();

    int w = t >> 6, l = t & 63;
    int m = l & 15, q4 = l >> 4;
    unsigned short* shw = sh16[w];

    const int NT16 = N_NODES / 16;
    const int WAVES = MFMA_GRID * 4;
    const int ITERS = (NT16 + WAVES - 1) / WAVES;

    for (int it = 0; it < ITERS; ++it) {
        int tl = it * WAVES + blockIdx.x * 4 + w;
        bool valid = tl < NT16;
        int nbase = tl * 16;

        if (valid) {
            const unsigned short* xr = in16 + (size_t)(nbase + m) * D + q4 * 8;
            short8 A0 = *(const short8*)(xr);
            short8 A1 = *(const short8*)(xr + 32);

#pragma unroll
            for (int nt = 0; nt < 8; nt++) {
                float bv = sb1[nt * 16 + m];
                floatx4 acc = {bv, bv, bv, bv};
                short8 B0 = *(const short8*)&sW1b[(0 * 8 + nt) * 512 + l * 8];
                short8 B1 = *(const short8*)&sW1b[(1 * 8 + nt) * 512 + l * 8];
                acc = __builtin_amdgcn_mfma_f32_16x16x32_bf16(A0, B0, acc, 0, 0, 0);
                acc = __builtin_amdgcn_mfma_f32_16x16x32_bf16(A1, B1, acc, 0, 0, 0);
#pragma unroll
                for (int r = 0; r < 4; r++)
                    shw[(q4 * 4 + r) * SH16_ST + nt * 16 + m] = f2bf(fmaxf(acc[r], 0.f));
            }
        }
        __syncthreads();

        if (valid) {
            short8 Ah[4];
#pragma unroll
            for (int kt = 0; kt < 4; kt++)
                Ah[kt] = *(const short8*)&shw[m * SH16_ST + kt * 32 + q4 * 8];
#pragma unroll
            for (int nt = 0; nt < 4; nt++) {
                float bv = sb2[nt * 16 + m];
                floatx4 acc = {bv, bv, bv, bv};
#pragma unroll
                for (int kt = 0; kt < 4; kt++) {
                    short8 B = *(const short8*)&sW2b[(kt * 4 + nt) * 512 + l * 8];
                    acc = __builtin_amdgcn_mfma_f32_16x16x32_bf16(Ah[kt], B, acc, 0, 0, 0);
                }
#pragma unroll
                for (int r = 0; r < 4; r++)
                    outp[(size_t)(nbase + q4 * 4 + r) * D + nt * 16 + m] = acc[r];
            }
        }
        __syncthreads();
    }
}

// ===========================================================================
// Tier-B/C fallbacks (unchanged, proven)
// ===========================================================================
__global__ __launch_bounds__(256) void k_zero(int* __restrict__ p, int n) {
    int i = blockIdx.x * 256 + threadIdx.x;
    if (i < n) p[i] = 0;
}

__global__ __launch_bounds__(256) void k_mlp_f32(float* __restrict__ io,
                                                 const float* __restrict__ W1,
                                                 const float* __restrict__ b1,
                                                 const float* __restrict__ W2,
                                                 const float* __restrict__ b2) {
    __shared__ unsigned short sW1b[8192];
    __shared__ unsigned short sW2b[8192];
    __shared__ float sh[4][16 * SH_STRIDE];
    __shared__ float sb1[H];
    __shared__ float sb2[D];

    int t = threadIdx.x;

    for (int q = t; q < 8192; q += 256) {
        int j = q & 7, l = (q >> 3) & 63, f = q >> 9;
        int nt = f & 7, kt = f >> 3;
        int k = kt * 32 + ((l >> 4) << 3) + j;
        int n = nt * 16 + (l & 15);
        sW1b[q] = f2bf(W1[k * H + n]);
    }
    for (int q = t; q < 8192; q += 256) {
        int j = q & 7, l = (q >> 3) & 63, f = q >> 9;
        int nt = f & 3, kt = f >> 2;
        int k = kt * 32 + ((l >> 4) << 3) + j;
        int n = nt * 16 + (l & 15);
        sW2b[q] = f2bf(W2[k * D + n]);
    }
    if (t < H) sb1[t] = b1[t];
    if (t >= H && t < H + D) sb2[t - H] = b2[t - H];
    __syncthreads();

    int w = t >> 6, l = t & 63;
    int m = l & 15, q4 = l >> 4;
    float* shw = sh[w];

    const int NT16 = N_NODES / 16;
    const int WAVES = 512 * 4;
    const int ITERS = (NT16 + WAVES - 1) / WAVES;

    for (int it = 0; it < ITERS; ++it) {
        int tl = it * WAVES + blockIdx.x * 4 + w;
        bool valid = tl < NT16;
        int nbase = tl * 16;

        if (valid) {
            const float* xr = io + (size_t)(nbase + m) * D + q4 * 8;
            float4 a0 = *(const float4*)(xr);
            float4 a1 = *(const float4*)(xr + 4);
            float4 c0 = *(const float4*)(xr + 32);
            float4 c1 = *(const float4*)(xr + 36);
            short8 A0, A1;
            A0[0] = f2bf(a0.x); A0[1] = f2bf(a0.y); A0[2] = f2bf(a0.z); A0[3] = f2bf(a0.w);
            A0[4] = f2bf(a1.x); A0[5] = f2bf(a1.y); A0[6] = f2bf(a1.z); A0[7] = f2bf(a1.w);
            A1[0] = f2bf(c0.x); A1[1] = f2bf(c0.y); A1[2] = f2bf(c0.z); A1[3] = f2bf(c0.w);
            A1[4] = f2bf(c1.x); A1[5] = f2bf(c1.y); A1[6] = f2bf(c1.z); A1[7] = f2bf(c1.w);

#pragma unroll
            for (int nt = 0; nt < 8; nt++) {
                float bv = sb1[nt * 16 + m];
                floatx4 acc = {bv, bv, bv, bv};
                short8 B0 = *(const short8*)&sW1b[(0 * 8 + nt) * 512 + l * 8];
                short8 B1 = *(const short8*)&sW1b[(1 * 8 + nt) * 512 + l * 8];
                acc = __builtin_amdgcn_mfma_f32_16x16x32_bf16(A0, B0, acc, 0, 0, 0);
                acc = __builtin_amdgcn_mfma_f32_16x16x32_bf16(A1, B1, acc, 0, 0, 0);
#pragma unroll
                for (int r = 0; r < 4; r++)
                    shw[(q4 * 4 + r) * SH_STRIDE + nt * 16 + m] = fmaxf(acc[r], 0.f);
            }
        }
        __syncthreads();

        if (valid) {
            short8 Ah[4];
#pragma unroll
            for (int kt = 0; kt < 4; kt++) {
                const float* hr = &shw[m * SH_STRIDE + kt * 32 + q4 * 8];
                float4 h0 = *(const float4*)(hr);
                float4 h1 = *(const float4*)(hr + 4);
                Ah[kt][0] = f2bf(h0.x); Ah[kt][1] = f2bf(h0.y);
                Ah[kt][2] = f2bf(h0.z); Ah[kt][3] = f2bf(h0.w);
                Ah[kt][4] = f2bf(h1.x); Ah[kt][5] = f2bf(h1.y);
                Ah[kt][6] = f2bf(h1.z); Ah[kt][7] = f2bf(h1.w);
            }
#pragma unroll
            for (int nt = 0; nt < 4; nt++) {
                float bv = sb2[nt * 16 + m];
                floatx4 acc = {bv, bv, bv, bv};
#pragma unroll
                for (int kt = 0; kt < 4; kt++) {
                    short8 B = *(const short8*)&sW2b[(kt * 4 + nt) * 512 + l * 8];
                    acc = __builtin_amdgcn_mfma_f32_16x16x32_bf16(Ah[kt], B, acc, 0, 0, 0);
                }
#pragma unroll
                for (int r = 0; r < 4; r++)
                    io[(size_t)(nbase + q4 * 4 + r) * D + nt * 16 + m] = acc[r];
            }
        }
        __syncthreads();
    }
}

__global__ __launch_bounds__(SCAN_BS) void k_scan1(const int* __restrict__ cnt,
                                                   int* __restrict__ ends,
                                                   int* __restrict__ bsum, int n) {
    __shared__ int s[SCAN_BS];
    int t = threadIdx.x, b = blockIdx.x;
    int id = b * SCAN_BS + t;
    s[t] = (id < n) ? cnt[id] : 0;
    __syncthreads();
    for (int off = 1; off < SCAN_BS; off <<= 1) {
        int u = (t >= off) ? s[t - off] : 0;
        __syncthreads();
        s[t] += u;
        __syncthreads();
    }
    if (id < n) ends[id] = s[t];
    if (t == SCAN_BS - 1) bsum[b] = s[t];
}

__global__ __launch_bounds__(256) void k_scan2(int* __restrict__ bsum, int nb) {
    __shared__ int s[256];
    int t = threadIdx.x;
    s[t] = (t < nb) ? bsum[t] : 0;
    __syncthreads();
    for (int off = 1; off < 256; off <<= 1) {
        int u = (t >= off) ? s[t - off] : 0;
        __syncthreads();
        s[t] += u;
        __syncthreads();
    }
    if (t < nb) bsum[t] = s[t];
}

__global__ __launch_bounds__(SCAN_BS) void k_scan3(int* __restrict__ ends,
                                                   const int* __restrict__ bsum, int n) {
    int t = threadIdx.x, b = blockIdx.x;
    int id = b * SCAN_BS + t;
    if (b > 0 && id < n) ends[id] += bsum[b - 1];
}

__global__ __launch_bounds__(256) void k_histpos(const int* __restrict__ dst,
                                                 int* __restrict__ cnt,
                                                 int* __restrict__ pos) {
    int e = blockIdx.x * 256 + threadIdx.x;
    if (e < N_EDGES) pos[e] = atomicAdd(&cnt[dst[e]], 1);
}

__global__ __launch_bounds__(256) void k_fill2(const int* __restrict__ src,
                                               const int* __restrict__ dst,
                                               const int* __restrict__ pos,
                                               const int* __restrict__ ends,
                                               int* __restrict__ csr) {
    int e = blockIdx.x * 256 + threadIdx.x;
    if (e >= N_EDGES) return;
    int d = dst[e];
    int start = (d > 0) ? ends[d - 1] : 0;
    csr[start + pos[e]] = src[e];
}

__global__ __launch_bounds__(256) void k_agg(const float* __restrict__ x,
                                             const int* __restrict__ csr,
                                             const int* __restrict__ ends,
                                             float* __restrict__ out) {
    int node = blockIdx.x * 4 + (threadIdx.x >> 6);
    if (node >= N_NODES) return;
    int f = threadIdx.x & 63;
    int start = (node > 0) ? ends[node - 1] : 0;
    int end = ends[node];
    float a0 = x[(size_t)node * D + f], a1 = 0.f, a2 = 0.f, a3 = 0.f;
    int e = start;
    for (; e + 4 <= end; e += 4) {
        int s0 = csr[e], s1 = csr[e + 1], s2 = csr[e + 2], s3 = csr[e + 3];
        a0 += x[(size_t)s0 * D + f];
        a1 += x[(size_t)s1 * D + f];
        a2 += x[(size_t)s2 * D + f];
        a3 += x[(size_t)s3 * D + f];
    }
    for (; e < end; e++) a0 += x[(size_t)csr[e] * D + f];
    out[(size_t)node * D + f] = (a0 + a1) + (a2 + a3);
}

__global__ __launch_bounds__(256) void k_init(const float4* __restrict__ x4,
                                              float4* __restrict__ agg4, int n4) {
    int i = blockIdx.x * 256 + threadIdx.x;
    if (i < n4) agg4[i] = x4[i];
}

__global__ __launch_bounds__(256) void k_scatter(const float4* __restrict__ x4,
                                                 const int* __restrict__ src,
                                                 const int* __restrict__ dst,
                                                 float* __restrict__ agg) {
    int gid = blockIdx.x * 256 + threadIdx.x;
    int e = gid >> 4;
    if (e >= N_EDGES) return;
    int c = gid & 15;
    float4 v = x4[src[e] * 16 + c];
    float* p = agg + (size_t)dst[e] * D + c * 4;
    atomicAdd(p + 0, v.x);
    atomicAdd(p + 1, v.y);
    atomicAdd(p + 2, v.z);
    atomicAdd(p + 3, v.w);
}

// ===========================================================================
extern "C" void kernel_launch(void* const* d_in, const int* in_sizes, int n_in,
                              void* d_out, int out_size, void* d_ws, size_t ws_size,
                              hipStream_t stream) {
    const float* x  = (const float*)d_in[0];
    const int* eidx = (const int*)d_in[1];   // [2, N_EDGES] int32 per harness
    const float* W1 = (const float*)d_in[2];
    const float* b1 = (const float*)d_in[3];
    const float* W2 = (const float*)d_in[4];
    const float* b2 = (const float*)d_in[5];
    float* out      = (float*)d_out;

    const int* src = eidx;
    const int* dst = eidx + N_EDGES;

    int ge = (N_EDGES + 255) / 256;
    int n4 = N_NODES * D / 4;

    // Tier A: x16[N*D bf16] o16[N*D bf16] ebuf[E] gW1b/gW2b[16384 bf16]
    //         bhist[NB2] ccur[NB2]                           ~= 32.1 MB
    size_t need_A = (size_t)N_NODES * D * 2 * sizeof(unsigned short)
                  + (size_t)N_EDGES * sizeof(int)
                  + (size_t)16384 * sizeof(unsigned short)
                  + (size_t)2 * NB2 * sizeof(int);
    // Tier B: cnt[N] ends[N] bsum[512] pos[E] csr[E] (~13.6 MB)
    size_t need_B = (size_t)(2 * N_NODES + 512 + 2 * N_EDGES) * sizeof(int);

    if (ws_size >= need_A) {
        unsigned short* x16 = (unsigned short*)d_ws;
        unsigned short* o16 = x16 + (size_t)N_NODES * D;
        int* ebuf   = (int*)(o16 + (size_t)N_NODES * D);
        unsigned short* gW1b = (unsigned short*)(ebuf + N_EDGES);
        unsigned short* gW2b = gW1b + 8192;
        int* bhist  = (int*)(gW2b + 8192);
        int* ccur   = bhist + NB2;

        // residency-clamped cooperative grid (computed once)
        static int G = 0;
        if (G == 0) {
            int nb = 0;
            if (hipOccupancyMaxActiveBlocksPerMultiprocessor(&nb, k_graph, 256, 0)
                    != hipSuccess || nb < 1)
                nb = 1;
            long g = (long)nb * 256;             // 256 CUs on MI355X
            if (g > 1024) g = 1024;
            if (g < 256) g = 256;
            G = (int)g;
        }

        hipMemsetAsync(bhist, 0, 2 * NB2 * sizeof(int), stream);

        const float* xa = x;
        unsigned short* x16a = x16;
        void* kargs[] = {(void*)&xa, (void*)&x16a, (void*)&src, (void*)&dst,
                         (void*)&W1, (void*)&W2, (void*)&gW1b, (void*)&gW2b,
                         (void*)&bhist, (void*)&ccur, (void*)&ebuf, (void*)&o16};
        hipError_t ce = hipLaunchCooperativeKernel(k_graph, dim3(G), dim3(256),
                                                   kargs, 0u, stream);
        if (ce != hipSuccess) {
            (void)hipGetLastError();             // clear; non-coop split
            k_p1<<<1024, 256, 0, stream>>>(x, x16, dst, W1, W2, gW1b, gW2b, bhist);
            k_p2<<<1024, 256, 0, stream>>>(src, dst, bhist, ccur, ebuf);
            k_p3<<<1024, 256, 0, stream>>>(x, x16, ebuf, bhist, o16);
        }
        k_mlp16<<<MFMA_GRID, 256, 0, stream>>>(o16, out, gW1b, gW2b, b1, b2);
    } else if (ws_size >= need_B) {
        int* cnt  = (int*)d_ws;
        int* ends = cnt + N_NODES;
        int* bsum = ends + N_NODES;
        int* pos  = bsum + 512;
        int* csr  = pos + N_EDGES;

        k_zero<<<(N_NODES + 255) / 256, 256, 0, stream>>>(cnt, N_NODES);
        k_histpos<<<ge, 256, 0, stream>>>(dst, cnt, pos);
        k_scan1<<<SCAN_NBLK, SCAN_BS, 0, stream>>>(cnt, ends, bsum, N_NODES);
        k_scan2<<<1, 256, 0, stream>>>(bsum, SCAN_NBLK);
        k_scan3<<<SCAN_NBLK, SCAN_BS, 0, stream>>>(ends, bsum, N_NODES);
        k_fill2<<<ge, 256, 0, stream>>>(src, dst, pos, ends, csr);
        k_agg<<<(N_NODES + 3) / 4, 256, 0, stream>>>(x, csr, ends, out);
        k_mlp_f32<<<512, 256, 0, stream>>>(out, W1, b1, W2, b2);
    } else {
        k_init<<<(n4 + 255) / 256, 256, 0, stream>>>((const float4*)x, (float4*)out, n4);
        long long total = (long long)N_EDGES * 16;
        k_scatter<<<(int)((total + 255) / 256), 256, 0, stream>>>(
            (const float4*)x, src, dst, out);
        k_mlp_f32<<<512, 256, 0, stream>>>(out, W1, b1, W2, b2);
    }
}

// Round 4
// 172.695 us; speedup vs baseline: 3.6048x; 3.6048x over previous
//
#include <hip/hip_runtime.h>

#define N_NODES 100000
#define N_EDGES 1600000
#define D 64
#define H 128
#define SCAN_BS 512
#define SCAN_NBLK ((N_NODES + SCAN_BS - 1) / SCAN_BS)   // 196

// bucket pipeline (R1-proven structure)
#define NB 1563                  // buckets of 64 nodes: 1563*64 >= 100000
#define NCHUNK 256
#define EPC (N_EDGES / NCHUNK)   // 6250 exactly
#define BCAP 2560                // LDS edge cap per tile (avg bucket = 1024)

#define MFMA_GRID 768
#define SH_STRIDE 132            // fp32 fallback MLP
#define SH16_ST 136              // bf16 sh stride

typedef __attribute__((ext_vector_type(8))) short short8;
typedef __attribute__((ext_vector_type(4))) float floatx4;
typedef __attribute__((ext_vector_type(4))) unsigned short ushort4_t;
typedef __attribute__((ext_vector_type(8))) unsigned short ushort8_t;

__device__ __forceinline__ unsigned short f2bf(float f) {
    unsigned u = __builtin_bit_cast(unsigned, f);
    u += 0x7FFFu + ((u >> 16) & 1u);
    return (unsigned short)(u >> 16);
}
__device__ __forceinline__ float bf2f(unsigned short u) {
    unsigned v = ((unsigned)u) << 16;
    return __builtin_bit_cast(float, v);
}

// ===========================================================================
// P0 fused (R1-proven): blocks [0,NCHUNK): per-chunk LDS bucket histogram
// -> M2 (coalesced). block NCHUNK / NCHUNK+1: W1/W2 -> bf16 MFMA layout.
// rest: x fp32 -> bf16 (grid-stride).
// ===========================================================================
__global__ __launch_bounds__(256) void k_pre(const float4* __restrict__ x4,
                                             ushort4_t* __restrict__ y, int n4,
                                             const int* __restrict__ dst,
                                             int* __restrict__ M2,
                                             const float* __restrict__ W1,
                                             const float* __restrict__ W2,
                                             unsigned short* __restrict__ gW1b,
                                             unsigned short* __restrict__ gW2b) {
    __shared__ int hist[NB];
    int t = threadIdx.x, blk = blockIdx.x;
    if (blk < NCHUNK) {
        int c = blk;
        for (int i = t; i < NB; i += 256) hist[i] = 0;
        __syncthreads();
        const int* dp = dst + c * EPC;
        for (int i = t; i < EPC; i += 256) atomicAdd(&hist[dp[i] >> 6], 1);
        __syncthreads();
        int* mp = M2 + c * NB;
        for (int i = t; i < NB; i += 256) mp[i] = hist[i];
    } else if (blk == NCHUNK) {
        for (int q = t; q < 8192; q += 256) {
            int j = q & 7, l = (q >> 3) & 63, f = q >> 9;
            int nt = f & 7, kt = f >> 3;
            int k = kt * 32 + ((l >> 4) << 3) + j;
            int n = nt * 16 + (l & 15);
            gW1b[q] = f2bf(W1[k * H + n]);
        }
    } else if (blk == NCHUNK + 1) {
        for (int q = t; q < 8192; q += 256) {
            int j = q & 7, l = (q >> 3) & 63, f = q >> 9;
            int nt = f & 3, kt = f >> 2;
            int k = kt * 32 + ((l >> 4) << 3) + j;
            int n = nt * 16 + (l & 15);
            gW2b[q] = f2bf(W2[k * D + n]);
        }
    } else {
        int cb = blk - NCHUNK - 2;
        int nconv = gridDim.x - NCHUNK - 2;
        for (int i = cb * 256 + t; i < n4; i += nconv * 256) {
            float4 v = x4[i];
            ushort4_t o;
            o[0] = f2bf(v.x); o[1] = f2bf(v.y); o[2] = f2bf(v.z); o[3] = f2bf(v.w);
            y[i] = o;
        }
    }
}

// ===========================================================================
// S1: column-wise exclusive scan of M2 over chunks, coalesced. (R1-proven)
// ===========================================================================
__global__ __launch_bounds__(256) void k_colscan(int* __restrict__ M2,
                                                 int* __restrict__ colsum) {
    int b = blockIdx.x * 256 + threadIdx.x;
    if (b >= NB) return;
    int run = 0;
    for (int c = 0; c < NCHUNK; c++) {
        int v = M2[c * NB + b];
        M2[c * NB + b] = run;
        run += v;
    }
    colsum[b] = run;
}

// ===========================================================================
// P3: partition edges into bucket-ordered ebuf, packed (dlow<<17)|src.
// Each block REDUNDANTLY scans colsum[NB] in LDS (L2-hot, ~1us, parallel)
// -> no separate k_bscan launch. Block 0 publishes gbends for k_bagg.
// LDS cursor atomics only; slice-exclusive global writes.
// ===========================================================================
__global__ __launch_bounds__(256) void k_part2(const int* __restrict__ src,
                                               const int* __restrict__ dst,
                                               const int* __restrict__ M2,
                                               const int* __restrict__ colsum,
                                               int* __restrict__ ebuf,
                                               int* __restrict__ gbends) {
    __shared__ int cur[NB];
    __shared__ int sbends[NB];       // inclusive bucket-edge prefix
    __shared__ int spart[256];
    int t = threadIdx.x, c = blockIdx.x;

    // local scan of colsum -> sbends (7 elems/thread: 256*7 = 1792 >= 1563)
    int base = t * 7;
    int v[7];
    int s = 0;
#pragma unroll
    for (int j = 0; j < 7; j++) {
        int idx = base + j;
        v[j] = (idx < NB) ? colsum[idx] : 0;
        s += v[j];
    }
    spart[t] = s;
    __syncthreads();
    for (int off = 1; off < 256; off <<= 1) {
        int u = (t >= off) ? spart[t - off] : 0;
        __syncthreads();
        spart[t] += u;
        __syncthreads();
    }
    int run = (t > 0) ? spart[t - 1] : 0;
#pragma unroll
    for (int j = 0; j < 7; j++) {
        int idx = base + j;
        run += v[j];
        if (idx < NB) sbends[idx] = run;   // inclusive
    }
    __syncthreads();

    const int* mp = M2 + c * NB;
    for (int i = t; i < NB; i += 256)
        cur[i] = ((i > 0) ? sbends[i - 1] : 0) + mp[i];
    if (c == 0)
        for (int i = t; i < NB; i += 256) gbends[i] = sbends[i];
    __syncthreads();

    const int* sp = src + c * EPC;
    const int* dp = dst + c * EPC;
    for (int i = t; i < EPC; i += 256) {
        int d = dp[i], srcv = sp[i];
        int p = atomicAdd(&cur[d >> 6], 1);
        ebuf[p] = srcv | ((d & 63) << 17);
    }
}

// ===========================================================================
// P4: one block per bucket. TILED mini-CSR in LDS (register accumulators
// persist across BCAP tiles -> no overflow path, no k_ovf launch; ntile==1
// in practice). Eighth-wave per node: 8 lanes/node x 16B bf16 gather loads.
// Epilogue adds fp32 x, writes bf16 o16. (R1 gather structure proven.)
// ===========================================================================
__global__ __launch_bounds__(256) void k_bagg5(const float* __restrict__ x,
                                               const unsigned short* __restrict__ x16,
                                               const int* __restrict__ ebuf,
                                               const int* __restrict__ gbends,
                                               unsigned short* __restrict__ o16) {
    __shared__ int scur[64];
    __shared__ int snd[64];          // inclusive ends per dlow (per tile)
    __shared__ int slist[BCAP];
    int t = threadIdx.x, b = blockIdx.x;
    int estart = (b > 0) ? gbends[b - 1] : 0;
    int ne = gbends[b] - estart;
    const int* ep = ebuf + estart;

    int g = t >> 3;                  // node-pair group 0..31
    int l8 = t & 7;                  // feature octet: feats l8*8 .. l8*8+7
    float aA0[8], aB0[8], aA1[8], aB1[8];
#pragma unroll
    for (int j = 0; j < 8; j++) { aA0[j] = 0.f; aB0[j] = 0.f; aA1[j] = 0.f; aB1[j] = 0.f; }

    int ntile = (ne + BCAP - 1) / BCAP;          // ==1 for Poisson(1024)
    for (int T = 0; T < ntile; T++) {
        int toff = T * BCAP;
        int tn = ne - toff;
        if (tn > BCAP) tn = BCAP;
        __syncthreads();                         // protect prev slist use
        if (t < 64) scur[t] = 0;
        __syncthreads();
        for (int i = t; i < tn; i += 256) atomicAdd(&scur[ep[toff + i] >> 17], 1);
        __syncthreads();
        if (t < 64) {
            int v = scur[t], s = v;
#pragma unroll
            for (int off = 1; off < 64; off <<= 1) {
                int u = __shfl_up(s, off, 64);
                if (t >= off) s += u;
            }
            snd[t] = s;
            scur[t] = s - v;                     // exclusive start -> cursor
        }
        __syncthreads();
        for (int i = t; i < tn; i += 256) {
            int v = ep[toff + i];
            int p = atomicAdd(&scur[v >> 17], 1);
            slist[p] = v & 0x1FFFF;
        }
        __syncthreads();

        // node 0 of pair
        {
            int dlow = g * 2;
            int s0 = (dlow > 0) ? snd[dlow - 1] : 0;
            int e1 = snd[dlow];
            int i2 = s0;
            for (; i2 + 2 <= e1; i2 += 2) {
                int sA = slist[i2], sB = slist[i2 + 1];
                ushort8_t uA = *(const ushort8_t*)&x16[(size_t)sA * D + l8 * 8];
                ushort8_t uB = *(const ushort8_t*)&x16[(size_t)sB * D + l8 * 8];
#pragma unroll
                for (int j = 0; j < 8; j++) aA0[j] += bf2f(uA[j]);
#pragma unroll
                for (int j = 0; j < 8; j++) aB0[j] += bf2f(uB[j]);
            }
            for (; i2 < e1; i2++) {
                ushort8_t uA = *(const ushort8_t*)&x16[(size_t)slist[i2] * D + l8 * 8];
#pragma unroll
                for (int j = 0; j < 8; j++) aA0[j] += bf2f(uA[j]);
            }
        }
        // node 1 of pair
        {
            int dlow = g * 2 + 1;
            int s0 = snd[dlow - 1];
            int e1 = snd[dlow];
            int i2 = s0;
            for (; i2 + 2 <= e1; i2 += 2) {
                int sA = slist[i2], sB = slist[i2 + 1];
                ushort8_t uA = *(const ushort8_t*)&x16[(size_t)sA * D + l8 * 8];
                ushort8_t uB = *(const ushort8_t*)&x16[(size_t)sB * D + l8 * 8];
#pragma unroll
                for (int j = 0; j < 8; j++) aA1[j] += bf2f(uA[j]);
#pragma unroll
                for (int j = 0; j < 8; j++) aB1[j] += bf2f(uB[j]);
            }
            for (; i2 < e1; i2++) {
                ushort8_t uA = *(const ushort8_t*)&x16[(size_t)slist[i2] * D + l8 * 8];
#pragma unroll
                for (int j = 0; j < 8; j++) aA1[j] += bf2f(uA[j]);
            }
        }
    }

    // epilogue: two nodes
#pragma unroll
    for (int k = 0; k < 2; k++) {
        int node = b * 64 + g * 2 + k;
        if (node < N_NODES) {
            const float* xp = x + (size_t)node * D + l8 * 8;
            float4 x0 = *(const float4*)xp;
            float4 x1 = *(const float4*)(xp + 4);
            float* pa = (k == 0) ? aA0 : aA1;
            float* pb = (k == 0) ? aB0 : aB1;
            ushort8_t o;
            o[0] = f2bf(pa[0] + pb[0] + x0.x);
            o[1] = f2bf(pa[1] + pb[1] + x0.y);
            o[2] = f2bf(pa[2] + pb[2] + x0.z);
            o[3] = f2bf(pa[3] + pb[3] + x0.w);
            o[4] = f2bf(pa[4] + pb[4] + x1.x);
            o[5] = f2bf(pa[5] + pb[5] + x1.y);
            o[6] = f2bf(pa[6] + pb[6] + x1.z);
            o[7] = f2bf(pa[7] + pb[7] + x1.w);
            *(ushort8_t*)&o16[(size_t)node * D + l8 * 8] = o;
        }
    }
}

// ===========================================================================
// MFMA bf16 fused MLP (R1-proven): bf16 in16, bf16 LDS h-staging, fp32 out.
// ===========================================================================
__global__ __launch_bounds__(256) void k_mlp16(const unsigned short* __restrict__ in16,
                                               float* __restrict__ outp,
                                               const unsigned short* __restrict__ gW1b,
                                               const unsigned short* __restrict__ gW2b,
                                               const float* __restrict__ b1,
                                               const float* __restrict__ b2) {
    __shared__ unsigned short sW1b[8192];
    __shared__ unsigned short sW2b[8192];
    __shared__ unsigned short sh16[4][16 * SH16_ST];
    __shared__ float sb1[H];
    __shared__ float sb2[D];

    int t = threadIdx.x;
    for (int q = t; q < 1024; q += 256) {
        *(short8*)&sW1b[q * 8] = *(const short8*)&gW1b[q * 8];
        *(short8*)&sW2b[q * 8] = *(const short8*)&gW2b[q * 8];
    }
    if (t < H) sb1[t] = b1[t];
    if (t >= H && t < H + D) sb2[t - H] = b2[t - H];
    __syncthreads();

    int w = t >> 6, l = t & 63;
    int m = l & 15, q4 = l >> 4;
    unsigned short* shw = sh16[w];

    const int NT16 = N_NODES / 16;
    const int WAVES = MFMA_GRID * 4;
    const int ITERS = (NT16 + WAVES - 1) / WAVES;

    for (int it = 0; it < ITERS; ++it) {
        int tl = it * WAVES + blockIdx.x * 4 + w;
        bool valid = tl < NT16;
        int nbase = tl * 16;

        if (valid) {
            const unsigned short* xr = in16 + (size_t)(nbase + m) * D + q4 * 8;
            short8 A0 = *(const short8*)(xr);
            short8 A1 = *(const short8*)(xr + 32);

#pragma unroll
            for (int nt = 0; nt < 8; nt++) {
                float bv = sb1[nt * 16 + m];
                floatx4 acc = {bv, bv, bv, bv};
                short8 B0 = *(const short8*)&sW1b[(0 * 8 + nt) * 512 + l * 8];
                short8 B1 = *(const short8*)&sW1b[(1 * 8 + nt) * 512 + l * 8];
                acc = __builtin_amdgcn_mfma_f32_16x16x32_bf16(A0, B0, acc, 0, 0, 0);
                acc = __builtin_amdgcn_mfma_f32_16x16x32_bf16(A1, B1, acc, 0, 0, 0);
#pragma unroll
                for (int r = 0; r < 4; r++)
                    shw[(q4 * 4 + r) * SH16_ST + nt * 16 + m] = f2bf(fmaxf(acc[r], 0.f));
            }
        }
        __syncthreads();

        if (valid) {
            short8 Ah[4];
#pragma unroll
            for (int kt = 0; kt < 4; kt++)
                Ah[kt] = *(const short8*)&shw[m * SH16_ST + kt * 32 + q4 * 8];
#pragma unroll
            for (int nt = 0; nt < 4; nt++) {
                float bv = sb2[nt * 16 + m];
                floatx4 acc = {bv, bv, bv, bv};
#pragma unroll
                for (int kt = 0; kt < 4; kt++) {
                    short8 B = *(const short8*)&sW2b[(kt * 4 + nt) * 512 + l * 8];
                    acc = __builtin_amdgcn_mfma_f32_16x16x32_bf16(Ah[kt], B, acc, 0, 0, 0);
                }
#pragma unroll
                for (int r = 0; r < 4; r++)
                    outp[(size_t)(nbase + q4 * 4 + r) * D + nt * 16 + m] = acc[r];
            }
        }
        __syncthreads();
    }
}

// ===========================================================================
// Tier-B/C fallbacks (unchanged, proven)
// ===========================================================================
__global__ __launch_bounds__(256) void k_zero(int* __restrict__ p, int n) {
    int i = blockIdx.x * 256 + threadIdx.x;
    if (i < n) p[i] = 0;
}

__global__ __launch_bounds__(256) void k_mlp_f32(float* __restrict__ io,
                                                 const float* __restrict__ W1,
                                                 const float* __restrict__ b1,
                                                 const float* __restrict__ W2,
                                                 const float* __restrict__ b2) {
    __shared__ unsigned short sW1b[8192];
    __shared__ unsigned short sW2b[8192];
    __shared__ float sh[4][16 * SH_STRIDE];
    __shared__ float sb1[H];
    __shared__ float sb2[D];

    int t = threadIdx.x;

    for (int q = t; q < 8192; q += 256) {
        int j = q & 7, l = (q >> 3) & 63, f = q >> 9;
        int nt = f & 7, kt = f >> 3;
        int k = kt * 32 + ((l >> 4) << 3) + j;
        int n = nt * 16 + (l & 15);
        sW1b[q] = f2bf(W1[k * H + n]);
    }
    for (int q = t; q < 8192; q += 256) {
        int j = q & 7, l = (q >> 3) & 63, f = q >> 9;
        int nt = f & 3, kt = f >> 2;
        int k = kt * 32 + ((l >> 4) << 3) + j;
        int n = nt * 16 + (l & 15);
        sW2b[q] = f2bf(W2[k * D + n]);
    }
    if (t < H) sb1[t] = b1[t];
    if (t >= H && t < H + D) sb2[t - H] = b2[t - H];
    __syncthreads();

    int w = t >> 6, l = t & 63;
    int m = l & 15, q4 = l >> 4;
    float* shw = sh[w];

    const int NT16 = N_NODES / 16;
    const int WAVES = 512 * 4;
    const int ITERS = (NT16 + WAVES - 1) / WAVES;

    for (int it = 0; it < ITERS; ++it) {
        int tl = it * WAVES + blockIdx.x * 4 + w;
        bool valid = tl < NT16;
        int nbase = tl * 16;

        if (valid) {
            const float* xr = io + (size_t)(nbase + m) * D + q4 * 8;
            float4 a0 = *(const float4*)(xr);
            float4 a1 = *(const float4*)(xr + 4);
            float4 c0 = *(const float4*)(xr + 32);
            float4 c1 = *(const float4*)(xr + 36);
            short8 A0, A1;
            A0[0] = f2bf(a0.x); A0[1] = f2bf(a0.y); A0[2] = f2bf(a0.z); A0[3] = f2bf(a0.w);
            A0[4] = f2bf(a1.x); A0[5] = f2bf(a1.y); A0[6] = f2bf(a1.z); A0[7] = f2bf(a1.w);
            A1[0] = f2bf(c0.x); A1[1] = f2bf(c0.y); A1[2] = f2bf(c0.z); A1[3] = f2bf(c0.w);
            A1[4] = f2bf(c1.x); A1[5] = f2bf(c1.y); A1[6] = f2bf(c1.z); A1[7] = f2bf(c1.w);

#pragma unroll
            for (int nt = 0; nt < 8; nt++) {
                float bv = sb1[nt * 16 + m];
                floatx4 acc = {bv, bv, bv, bv};
                short8 B0 = *(const short8*)&sW1b[(0 * 8 + nt) * 512 + l * 8];
                short8 B1 = *(const short8*)&sW1b[(1 * 8 + nt) * 512 + l * 8];
                acc = __builtin_amdgcn_mfma_f32_16x16x32_bf16(A0, B0, acc, 0, 0, 0);
                acc = __builtin_amdgcn_mfma_f32_16x16x32_bf16(A1, B1, acc, 0, 0, 0);
#pragma unroll
                for (int r = 0; r < 4; r++)
                    shw[(q4 * 4 + r) * SH_STRIDE + nt * 16 + m] = fmaxf(acc[r], 0.f);
            }
        }
        __syncthreads();

        if (valid) {
            short8 Ah[4];
#pragma unroll
            for (int kt = 0; kt < 4; kt++) {
                const float* hr = &shw[m * SH_STRIDE + kt * 32 + q4 * 8];
                float4 h0 = *(const float4*)(hr);
                float4 h1 = *(const float4*)(hr + 4);
                Ah[kt][0] = f2bf(h0.x); Ah[kt][1] = f2bf(h0.y);
                Ah[kt][2] = f2bf(h0.z); Ah[kt][3] = f2bf(h0.w);
                Ah[kt][4] = f2bf(h1.x); Ah[kt][5] = f2bf(h1.y);
                Ah[kt][6] = f2bf(h1.z); Ah[kt][7] = f2bf(h1.w);
            }
#pragma unroll
            for (int nt = 0; nt < 4; nt++) {
                float bv = sb2[nt * 16 + m];
                floatx4 acc = {bv, bv, bv, bv};
#pragma unroll
                for (int kt = 0; kt < 4; kt++) {
                    short8 B = *(const short8*)&sW2b[(kt * 4 + nt) * 512 + l * 8];
                    acc = __builtin_amdgcn_mfma_f32_16x16x32_bf16(Ah[kt], B, acc, 0, 0, 0);
                }
#pragma unroll
                for (int r = 0; r < 4; r++)
                    io[(size_t)(nbase + q4 * 4 + r) * D + nt * 16 + m] = acc[r];
            }
        }
        __syncthreads();
    }
}

__global__ __launch_bounds__(SCAN_BS) void k_scan1(const int* __restrict__ cnt,
                                                   int* __restrict__ ends,
                                                   int* __restrict__ bsum, int n) {
    __shared__ int s[SCAN_BS];
    int t = threadIdx.x, b = blockIdx.x;
    int id = b * SCAN_BS + t;
    s[t] = (id < n) ? cnt[id] : 0;
    __syncthreads();
    for (int off = 1; off < SCAN_BS; off <<= 1) {
        int u = (t >= off) ? s[t - off] : 0;
        __syncthreads();
        s[t] += u;
        __syncthreads();
    }
    if (id < n) ends[id] = s[t];
    if (t == SCAN_BS - 1) bsum[b] = s[t];
}

__global__ __launch_bounds__(256) void k_scan2(int* __restrict__ bsum, int nb) {
    __shared__ int s[256];
    int t = threadIdx.x;
    s[t] = (t < nb) ? bsum[t] : 0;
    __syncthreads();
    for (int off = 1; off < 256; off <<= 1) {
        int u = (t >= off) ? s[t - off] : 0;
        __syncthreads();
        s[t] += u;
        __syncthreads();
    }
    if (t < nb) bsum[t] = s[t];
}

__global__ __launch_bounds__(SCAN_BS) void k_scan3(int* __restrict__ ends,
                                                   const int* __restrict__ bsum, int n) {
    int t = threadIdx.x, b = blockIdx.x;
    int id = b * SCAN_BS + t;
    if (b > 0 && id < n) ends[id] += bsum[b - 1];
}

__global__ __launch_bounds__(256) void k_histpos(const int* __restrict__ dst,
                                                 int* __restrict__ cnt,
                                                 int* __restrict__ pos) {
    int e = blockIdx.x * 256 + threadIdx.x;
    if (e < N_EDGES) pos[e] = atomicAdd(&cnt[dst[e]], 1);
}

__global__ __launch_bounds__(256) void k_fill2(const int* __restrict__ src,
                                               const int* __restrict__ dst,
                                               const int* __restrict__ pos,
                                               const int* __restrict__ ends,
                                               int* __restrict__ csr) {
    int e = blockIdx.x * 256 + threadIdx.x;
    if (e >= N_EDGES) return;
    int d = dst[e];
    int start = (d > 0) ? ends[d - 1] : 0;
    csr[start + pos[e]] = src[e];
}

__global__ __launch_bounds__(256) void k_agg(const float* __restrict__ x,
                                             const int* __restrict__ csr,
                                             const int* __restrict__ ends,
                                             float* __restrict__ out) {
    int node = blockIdx.x * 4 + (threadIdx.x >> 6);
    if (node >= N_NODES) return;
    int f = threadIdx.x & 63;
    int start = (node > 0) ? ends[node - 1] : 0;
    int end = ends[node];
    float a0 = x[(size_t)node * D + f], a1 = 0.f, a2 = 0.f, a3 = 0.f;
    int e = start;
    for (; e + 4 <= end; e += 4) {
        int s0 = csr[e], s1 = csr[e + 1], s2 = csr[e + 2], s3 = csr[e + 3];
        a0 += x[(size_t)s0 * D + f];
        a1 += x[(size_t)s1 * D + f];
        a2 += x[(size_t)s2 * D + f];
        a3 += x[(size_t)s3 * D + f];
    }
    for (; e < end; e++) a0 += x[(size_t)csr[e] * D + f];
    out[(size_t)node * D + f] = (a0 + a1) + (a2 + a3);
}

__global__ __launch_bounds__(256) void k_init(const float4* __restrict__ x4,
                                              float4* __restrict__ agg4, int n4) {
    int i = blockIdx.x * 256 + threadIdx.x;
    if (i < n4) agg4[i] = x4[i];
}

__global__ __launch_bounds__(256) void k_scatter(const float4* __restrict__ x4,
                                                 const int* __restrict__ src,
                                                 const int* __restrict__ dst,
                                                 float* __restrict__ agg) {
    int gid = blockIdx.x * 256 + threadIdx.x;
    int e = gid >> 4;
    if (e >= N_EDGES) return;
    int c = gid & 15;
    float4 v = x4[src[e] * 16 + c];
    float* p = agg + (size_t)dst[e] * D + c * 4;
    atomicAdd(p + 0, v.x);
    atomicAdd(p + 1, v.y);
    atomicAdd(p + 2, v.z);
    atomicAdd(p + 3, v.w);
}

// ===========================================================================
extern "C" void kernel_launch(void* const* d_in, const int* in_sizes, int n_in,
                              void* d_out, int out_size, void* d_ws, size_t ws_size,
                              hipStream_t stream) {
    const float* x  = (const float*)d_in[0];
    const int* eidx = (const int*)d_in[1];   // [2, N_EDGES] int32 per harness
    const float* W1 = (const float*)d_in[2];
    const float* b1 = (const float*)d_in[3];
    const float* W2 = (const float*)d_in[4];
    const float* b2 = (const float*)d_in[5];
    float* out      = (float*)d_out;

    const int* src = eidx;
    const int* dst = eidx + N_EDGES;

    int ge = (N_EDGES + 255) / 256;
    int n4 = N_NODES * D / 4;

    // Tier A: x16[N*D bf16] o16[N*D bf16] ebuf[E] gW1b/gW2b M2[NCHUNK*NB]
    //         colsum[NB] gbends[NB]                          ~= 33.7 MB
    size_t need_A = (size_t)N_NODES * D * 2 * sizeof(unsigned short)
                  + (size_t)N_EDGES * sizeof(int)
                  + (size_t)16384 * sizeof(unsigned short)
                  + (size_t)(NCHUNK * NB + 2 * NB) * sizeof(int);
    // Tier B: cnt[N] ends[N] bsum[512] pos[E] csr[E] (~13.6 MB)
    size_t need_B = (size_t)(2 * N_NODES + 512 + 2 * N_EDGES) * sizeof(int);

    if (ws_size >= need_A) {
        unsigned short* x16 = (unsigned short*)d_ws;
        unsigned short* o16 = x16 + (size_t)N_NODES * D;
        int* ebuf   = (int*)(o16 + (size_t)N_NODES * D);
        unsigned short* gW1b = (unsigned short*)(ebuf + N_EDGES);
        unsigned short* gW2b = gW1b + 8192;
        int* M2     = (int*)(gW2b + 8192);
        int* colsum = M2 + NCHUNK * NB;
        int* gbends = colsum + NB;

        k_pre<<<NCHUNK + 2 + 2048, 256, 0, stream>>>((const float4*)x, (ushort4_t*)x16,
                                                     n4, dst, M2, W1, W2, gW1b, gW2b);
        k_colscan<<<(NB + 255) / 256, 256, 0, stream>>>(M2, colsum);
        k_part2<<<NCHUNK, 256, 0, stream>>>(src, dst, M2, colsum, ebuf, gbends);
        k_bagg5<<<NB, 256, 0, stream>>>(x, x16, ebuf, gbends, o16);
        k_mlp16<<<MFMA_GRID, 256, 0, stream>>>(o16, out, gW1b, gW2b, b1, b2);
    } else if (ws_size >= need_B) {
        int* cnt  = (int*)d_ws;
        int* ends = cnt + N_NODES;
        int* bsum = ends + N_NODES;
        int* pos  = bsum + 512;
        int* csr  = pos + N_EDGES;

        k_zero<<<(N_NODES + 255) / 256, 256, 0, stream>>>(cnt, N_NODES);
        k_histpos<<<ge, 256, 0, stream>>>(dst, cnt, pos);
        k_scan1<<<SCAN_NBLK, SCAN_BS, 0, stream>>>(cnt, ends, bsum, N_NODES);
        k_scan2<<<1, 256, 0, stream>>>(bsum, SCAN_NBLK);
        k_scan3<<<SCAN_NBLK, SCAN_BS, 0, stream>>>(ends, bsum, N_NODES);
        k_fill2<<<ge, 256, 0, stream>>>(src, dst, pos, ends, csr);
        k_agg<<<(N_NODES + 3) / 4, 256, 0, stream>>>(x, csr, ends, out);
        k_mlp_f32<<<512, 256, 0, stream>>>(out, W1, b1, W2, b2);
    } else {
        k_init<<<(n4 + 255) / 256, 256, 0, stream>>>((const float4*)x, (float4*)out, n4);
        long long total = (long long)N_EDGES * 16;
        k_scatter<<<(int)((total + 255) / 256), 256, 0, stream>>>(
            (const float4*)x, src, dst, out);
        k_mlp_f32<<<512, 256, 0, stream>>>(out, W1, b1, W2, b2);
    }
}